// Round 1
// 687.593 us; speedup vs baseline: 1.2248x; 1.2248x over previous
//
#include <hip/hip_runtime.h>
#include <math.h>

// Tril2Diff: out[b] = L @ L^T where L is 128x128 lower-triangular scattered
// from x[b] (8256 tril values), diagonal replaced by log1p(exp(d)+1e-12).
//
// Memory-bound target: ~807 MB traffic -> ~128us floor. Previous version was
// VALU-bound (75% VALUBusy) on per-element sqrt/while index math + divergent
// softplus. This version:
//  - compile-time table of LDS byte offsets for the tril scatter (16.5 KB,
//    L2-resident; killed the sqrt/div/while per element)
//  - float4/ushort4 vectorized scatter loads
//  - diagonal softplus as a separate convergent 128-thread pass
//  - skip k>=64 MFMA steps for the three quadrants that only touch rows 0..63
//    (L is lower-triangular -> those products are all zero)

#define DIM        128
#define NTRIL      8256          // 128*129/2
#define LDS_STRIDE 136           // bf16 per row: 128 + 8 pad (kills 32-way conflicts)
#define ROW_BYTES  272

typedef __bf16 bf16x8 __attribute__((ext_vector_type(8)));
typedef float  f32x16 __attribute__((ext_vector_type(16)));

// ---- compile-time scatter table: flat tril index -> LDS byte offset ----
struct RcTab { unsigned short off[NTRIL]; };
static constexpr RcTab make_tab() {
    RcTab t{};
    int idx = 0;
    for (int r = 0; r < DIM; ++r)
        for (int c = 0; c <= r; ++c)
            t.off[idx++] = (unsigned short)((r * LDS_STRIDE + c) * 2);
    return t;
}
__device__ const RcTab TBL = make_tab();

__global__ __launch_bounds__(256) void tril2diff_kernel(
    const float* __restrict__ x, float* __restrict__ out)
{
    __shared__ alignas(16) __bf16 Lsh[DIM * LDS_STRIDE];

    const int b   = blockIdx.x;
    const int tid = threadIdx.x;

    // ---- phase 0: zero LDS (upper triangle + pad must be 0 for MFMA) ----
    // 128*136 bf16 = 34816 B = 2176 uint4 = 8.5 * 256
    uint4* lz4 = (uint4*)Lsh;
    #pragma unroll
    for (int i = 0; i < 8; ++i)
        lz4[tid + i * 256] = uint4{0u, 0u, 0u, 0u};
    if (tid < 128)
        lz4[2048 + tid] = uint4{0u, 0u, 0u, 0u};
    __syncthreads();

    // ---- phase 1: scatter x -> L (bf16), table-driven, 4-wide ----
    // 8256/4 = 2064 chunks = 8*256 + 16
    const float* xb = x + (size_t)b * NTRIL;
    char* lbw = (char*)Lsh;
    #pragma unroll
    for (int i = 0; i < 8; ++i) {
        const int t4 = (tid + i * 256) * 4;
        const float4  v = *(const float4*)(xb + t4);
        const ushort4 o = *(const ushort4*)(TBL.off + t4);
        *(__bf16*)(lbw + o.x) = (__bf16)v.x;
        *(__bf16*)(lbw + o.y) = (__bf16)v.y;
        *(__bf16*)(lbw + o.z) = (__bf16)v.z;
        *(__bf16*)(lbw + o.w) = (__bf16)v.w;
    }
    if (tid < 16) {
        const int t4 = (2048 + tid) * 4;
        const float4  v = *(const float4*)(xb + t4);
        const ushort4 o = *(const ushort4*)(TBL.off + t4);
        *(__bf16*)(lbw + o.x) = (__bf16)v.x;
        *(__bf16*)(lbw + o.y) = (__bf16)v.y;
        *(__bf16*)(lbw + o.z) = (__bf16)v.z;
        *(__bf16*)(lbw + o.w) = (__bf16)v.w;
    }
    __syncthreads();

    // ---- phase 1b: softplus diagonal, convergent (one thread per row) ----
    if (tid < DIM) {
        const int r = tid;
        const int t = (r * (r + 1)) / 2 + r;      // flat index of L[r][r]
        float v = xb[t];                          // L1/L2 hit (just streamed)
        v = log1pf(expf(v) + 1e-12f);
        Lsh[r * LDS_STRIDE + r] = (__bf16)v;
    }
    __syncthreads();

    // ---- phase 2: C = L * L^T via 32x32x16 bf16 MFMA ----
    // 4 waves; wave w owns the 64x64 quadrant (w>>1, w&1), as 2x2 tiles of 32x32.
    // A-frag rows = i-block rows of L; B-frag (B = L^T) rows = j-block rows of L.
    // L[.,k]==0 for k>=64 in rows 0..63 -> quadrants other than (1,1) only
    // need k-steps 0..3.
    const int lane = tid & 63;
    const int wv   = tid >> 6;
    const int i0   = (wv >> 1) * 64;
    const int j0   = (wv & 1) * 64;
    const int cl   = lane & 31;      // row-within-32-block (A) / col (B) selector
    const int hh   = lane >> 5;      // k-half selector

    f32x16 acc00 = {0}, acc01 = {0}, acc10 = {0}, acc11 = {0};
    const char* lb = (const char*)Lsh;

#define MFMA_STEP(ks)                                                          \
    {                                                                          \
        const int koff = (ks) * 32 + hh * 16;                                  \
        bf16x8 a0 = *(const bf16x8*)(lb + (i0      + cl) * ROW_BYTES + koff);  \
        bf16x8 a1 = *(const bf16x8*)(lb + (i0 + 32 + cl) * ROW_BYTES + koff);  \
        bf16x8 b0 = *(const bf16x8*)(lb + (j0      + cl) * ROW_BYTES + koff);  \
        bf16x8 b1 = *(const bf16x8*)(lb + (j0 + 32 + cl) * ROW_BYTES + koff);  \
        acc00 = __builtin_amdgcn_mfma_f32_32x32x16_bf16(a0, b0, acc00, 0, 0, 0); \
        acc01 = __builtin_amdgcn_mfma_f32_32x32x16_bf16(a0, b1, acc01, 0, 0, 0); \
        acc10 = __builtin_amdgcn_mfma_f32_32x32x16_bf16(a1, b0, acc10, 0, 0, 0); \
        acc11 = __builtin_amdgcn_mfma_f32_32x32x16_bf16(a1, b1, acc11, 0, 0, 0); \
    }

    #pragma unroll
    for (int ks = 0; ks < 4; ++ks)
        MFMA_STEP(ks);
    if (wv == 3) {
        #pragma unroll
        for (int ks = 4; ks < 8; ++ks)
            MFMA_STEP(ks);
    }
#undef MFMA_STEP

    // ---- phase 3: store (C/D layout: col=lane&31, row=(reg&3)+8*(reg>>2)+4*(lane>>5)) ----
    // Each 32-lane half-wave writes 128 contiguous bytes per store -> coalesced.
    float* ob = out + (size_t)b * (DIM * DIM);
    #pragma unroll
    for (int reg = 0; reg < 16; ++reg) {
        const int row = (reg & 3) + 8 * (reg >> 2) + 4 * hh;
        ob[(i0      + row) * DIM + j0      + cl] = acc00[reg];
        ob[(i0      + row) * DIM + j0 + 32 + cl] = acc01[reg];
        ob[(i0 + 32 + row) * DIM + j0      + cl] = acc10[reg];
        ob[(i0 + 32 + row) * DIM + j0 + 32 + cl] = acc11[reg];
    }
}

extern "C" void kernel_launch(void* const* d_in, const int* in_sizes, int n_in,
                              void* d_out, int out_size, void* d_ws, size_t ws_size,
                              hipStream_t stream) {
    const float* x = (const float*)d_in[0];
    float* out = (float*)d_out;
    const int batch = in_sizes[0] / NTRIL;   // 8192
    tril2diff_kernel<<<batch, 256, 0, stream>>>(x, out);
}

// Round 2
// 680.740 us; speedup vs baseline: 1.2371x; 1.0101x over previous
//
#include <hip/hip_runtime.h>
#include <math.h>

// Tril2Diff: out[b] = L @ L^T where L is 128x128 lower-triangular scattered
// from x[b] (8256 tril values), diagonal replaced by log1p(exp(d)+1e-12).
//
// Memory-bound target: ~807 MB traffic -> ~110-128us HBM floor.
// R1 killed the VALU bottleneck (table-driven scatter). R2 targets
// latency/concurrency:
//  - LDS 34816 -> 32768 B (stride 256 + XOR swizzle byte^=(row&7)<<4 instead
//    of +8 pad) => 5 blocks/CU instead of 4 (LDS-capped occupancy +25%)
//  - all global loads issued into registers BEFORE the LDS zero phase
//    (HBM latency hides under zero-fill instead of stalling post-barrier)
//  - diagonal softplus computed during scatter (reg), written in a tiny 1b phase
//  - k>=64 MFMA steps skipped for the three quadrants touching rows 0..63

#define DIM        128
#define NTRIL      8256          // 128*129/2
#define ROW_BYTES  256           // bf16 row, no pad; XOR swizzle kills conflicts

typedef __bf16 bf16x8 __attribute__((ext_vector_type(8)));
typedef float  f32x16 __attribute__((ext_vector_type(16)));

// ---- compile-time scatter table: flat tril index -> swizzled LDS byte offset ----
struct RcTab { unsigned short off[NTRIL]; };
static constexpr RcTab make_tab() {
    RcTab t{};
    int idx = 0;
    for (int r = 0; r < DIM; ++r)
        for (int c = 0; c <= r; ++c)
            t.off[idx++] = (unsigned short)((r * ROW_BYTES + c * 2) ^ ((r & 7) << 4));
    return t;
}
__device__ const RcTab TBL = make_tab();

__device__ __forceinline__ int rowbase(int r) {   // swizzled base byte of row r
    return (r << 8) ^ ((r & 7) << 4);
}

__global__ __launch_bounds__(256) void tril2diff_kernel(
    const float* __restrict__ x, float* __restrict__ out)
{
    __shared__ alignas(16) __bf16 Lsh[DIM * ROW_BYTES / 2];   // 32768 B exactly

    const int b   = blockIdx.x;
    const int tid = threadIdx.x;
    const float* xb = x + (size_t)b * NTRIL;

    // ---- phase A: issue ALL global loads first (latency hides under zeroing) ----
    float4  v[8];
    ushort4 o[8];
    #pragma unroll
    for (int i = 0; i < 8; ++i) {
        const int t4 = (tid + i * 256) * 4;
        v[i] = *(const float4*)(xb + t4);
        o[i] = *(const ushort4*)(TBL.off + t4);
    }
    float4 vt; ushort4 ot;
    if (tid < 16) {                       // tail: 8256/4 = 2064 = 8*256 + 16
        const int t4 = (2048 + tid) * 4;
        vt = *(const float4*)(xb + t4);
        ot = *(const ushort4*)(TBL.off + t4);
    }
    float dvx;
    if (tid < DIM)                        // diagonal element of row tid
        dvx = xb[(tid * (tid + 1)) / 2 + tid];

    // ---- phase 0: zero LDS (upper triangle must be 0 for MFMA) ----
    // 32768 B = 2048 uint4 = 8 * 256
    uint4* lz4 = (uint4*)Lsh;
    #pragma unroll
    for (int i = 0; i < 8; ++i)
        lz4[tid + i * 256] = uint4{0u, 0u, 0u, 0u};
    __syncthreads();

    // ---- phase 1: scatter x -> L (bf16), table-driven (swizzle baked in) ----
    char* lbw = (char*)Lsh;
    #pragma unroll
    for (int i = 0; i < 8; ++i) {
        *(__bf16*)(lbw + o[i].x) = (__bf16)v[i].x;
        *(__bf16*)(lbw + o[i].y) = (__bf16)v[i].y;
        *(__bf16*)(lbw + o[i].z) = (__bf16)v[i].z;
        *(__bf16*)(lbw + o[i].w) = (__bf16)v[i].w;
    }
    if (tid < 16) {
        *(__bf16*)(lbw + ot.x) = (__bf16)vt.x;
        *(__bf16*)(lbw + ot.y) = (__bf16)vt.y;
        *(__bf16*)(lbw + ot.z) = (__bf16)vt.z;
        *(__bf16*)(lbw + ot.w) = (__bf16)vt.w;
    }
    // softplus computed here: VALU overlaps other waves' scatter
    float dv;
    if (tid < DIM)
        dv = log1pf(expf(dvx) + 1e-12f);
    __syncthreads();

    // ---- phase 1b: overwrite diagonal (tiny, convergent) ----
    if (tid < DIM)
        *(__bf16*)(lbw + ((tid * ROW_BYTES + tid * 2) ^ ((tid & 7) << 4))) = (__bf16)dv;
    __syncthreads();

    // ---- phase 2: C = L * L^T via 32x32x16 bf16 MFMA ----
    // 4 waves; wave w owns the 64x64 quadrant (w>>1, w&1), as 2x2 tiles of 32x32.
    // A-frag rows = i-block rows of L; B-frag (B = L^T) rows = j-block rows of L.
    // L[.,k]==0 for k>=64 in rows 0..63 -> quadrants other than (1,1) only
    // need k-steps 0..3.
    const int lane = tid & 63;
    const int wv   = tid >> 6;
    const int i0   = (wv >> 1) * 64;
    const int j0   = (wv & 1) * 64;
    const int cl   = lane & 31;      // row-within-32-block (A) / col (B) selector
    const int hh   = lane >> 5;      // k-half selector
    const int kb   = hh * 16;

    const int ba0 = rowbase(i0      + cl);
    const int ba1 = rowbase(i0 + 32 + cl);
    const int bb0 = rowbase(j0      + cl);
    const int bb1 = rowbase(j0 + 32 + cl);

    f32x16 acc00 = {0}, acc01 = {0}, acc10 = {0}, acc11 = {0};
    const char* lb = (const char*)Lsh;

    // addr = rowbase ^ koff is exact: rowbase bits {>=8, 4..6}, koff bits {4..7},
    // and XOR reproduces (row<<8) | (koff ^ swz) since bit-8+ never collides.
#define MFMA_STEP(ks)                                                          \
    {                                                                          \
        const int koff = (ks) * 32 + kb;                                       \
        bf16x8 a0 = *(const bf16x8*)(lb + (ba0 ^ koff));                       \
        bf16x8 a1 = *(const bf16x8*)(lb + (ba1 ^ koff));                       \
        bf16x8 b0 = *(const bf16x8*)(lb + (bb0 ^ koff));                       \
        bf16x8 b1 = *(const bf16x8*)(lb + (bb1 ^ koff));                       \
        acc00 = __builtin_amdgcn_mfma_f32_32x32x16_bf16(a0, b0, acc00, 0, 0, 0); \
        acc01 = __builtin_amdgcn_mfma_f32_32x32x16_bf16(a0, b1, acc01, 0, 0, 0); \
        acc10 = __builtin_amdgcn_mfma_f32_32x32x16_bf16(a1, b0, acc10, 0, 0, 0); \
        acc11 = __builtin_amdgcn_mfma_f32_32x32x16_bf16(a1, b1, acc11, 0, 0, 0); \
    }

    #pragma unroll
    for (int ks = 0; ks < 4; ++ks)
        MFMA_STEP(ks);
    if (wv == 3) {
        #pragma unroll
        for (int ks = 4; ks < 8; ++ks)
            MFMA_STEP(ks);
    }
#undef MFMA_STEP

    // ---- phase 3: store (C/D layout: col=lane&31, row=(reg&3)+8*(reg>>2)+4*(lane>>5)) ----
    // Each 32-lane half-wave writes 128 contiguous bytes per store -> coalesced.
    float* ob = out + (size_t)b * (DIM * DIM);
    #pragma unroll
    for (int reg = 0; reg < 16; ++reg) {
        const int row = (reg & 3) + 8 * (reg >> 2) + 4 * hh;
        ob[(i0      + row) * DIM + j0      + cl] = acc00[reg];
        ob[(i0      + row) * DIM + j0 + 32 + cl] = acc01[reg];
        ob[(i0 + 32 + row) * DIM + j0      + cl] = acc10[reg];
        ob[(i0 + 32 + row) * DIM + j0 + 32 + cl] = acc11[reg];
    }
}

extern "C" void kernel_launch(void* const* d_in, const int* in_sizes, int n_in,
                              void* d_out, int out_size, void* d_ws, size_t ws_size,
                              hipStream_t stream) {
    const float* x = (const float*)d_in[0];
    float* out = (float*)d_out;
    const int batch = in_sizes[0] / NTRIL;   // 8192
    tril2diff_kernel<<<batch, 256, 0, stream>>>(x, out);
}